// Round 6
// baseline (396.684 us; speedup 1.0000x reference)
//
#include <hip/hip_runtime.h>
#include <hip/hip_bf16.h>
#include <stdint.h>

// EuclideanDeconf: x[B,D] fp32, W[C,D] fp32 -> out[B,C] fp32
// out = (2/D)*x.W^T - ||x||^2/D - ||w||^2/D
// R9: SINGLE fused kernel. The separate pack pass (fp32->bf16 repack + norms)
// cost 85-104 µs across R0-R5 no matter how it was written (extra 108 MB HBM
// round-trip + atomic contention / shfl chains). Fused: each block converts
// its own fp32 panels to bf16 fragments in-register per K-step (re-reads are
// L2-hot: A-panel 512 KB x 16 sharing blocks on one XCD via slab swizzle;
// B 8 MB is L3-resident) and computes row norms from the pre-conversion fp32
// values with zero atomics.
#define B_ROWS 16384
#define D_DIM  1024
#define C_DIM  2048
#define KT32   32              // K-steps of 32

typedef short bf16x8 __attribute__((ext_vector_type(8)));   // 8 bf16 = 4 VGPRs
typedef float f32x4  __attribute__((ext_vector_type(4)));

#define PRIO1 __builtin_amdgcn_s_setprio(1)
#define PRIO0 __builtin_amdgcn_s_setprio(0)

__device__ __forceinline__ float sq4(f32x4 v) {
    return v[0]*v[0] + v[1]*v[1] + v[2]*v[2] + v[3]*v[3];
}

// pack 8 fp32 (lo,hi) -> bf16x8 (RNE, same as reference-passing pack kernels)
__device__ __forceinline__ void pk8(ushort* dst, f32x4 lo, f32x4 hi) {
    ushort u[8]; __hip_bfloat16 h;
    h = __float2bfloat16(lo[0]); u[0] = *(const ushort*)&h;
    h = __float2bfloat16(lo[1]); u[1] = *(const ushort*)&h;
    h = __float2bfloat16(lo[2]); u[2] = *(const ushort*)&h;
    h = __float2bfloat16(lo[3]); u[3] = *(const ushort*)&h;
    h = __float2bfloat16(hi[0]); u[4] = *(const ushort*)&h;
    h = __float2bfloat16(hi[1]); u[5] = *(const ushort*)&h;
    h = __float2bfloat16(hi[2]); u[6] = *(const ushort*)&h;
    h = __float2bfloat16(hi[3]); u[7] = *(const ushort*)&h;
    *(bf16x8*)dst = *(const bf16x8*)u;
}

// ---------------------------------------------------------------------------
// gemm_fused: 128x128 tile, 4 waves 2x2 (wave tile 64x64), BK=32,
// double-buffered bf16 LDS (2 x 16 KB) + 1 KB norms = 33 KB -> 3 blocks/CU
// (VGPR-capped). Per K-step per wave:
//   8 ds_read_b128 bf16 frags (conflict-free, chunk layout as R0-R5)
//   8 global f32x4 loads: lane reads its OWN next-step fragment (32 B
//     contiguous: row=lane&15 of the tile, floats kt*32+(lane>>4)*8..+7 —
//     the 4 lanes {r,r+16,r+32,r+48} cover each row's 128 B exactly; L2-hot)
//   16 MFMA (setprio)
//   norm accumulate (fp32 squares of loaded values) + cvt -> 4 ds_write_b128
//     into the other buffer
//   __syncthreads()   (one barrier per step; loads consumed before it, so
//                      no manual vmcnt needed — nothing crosses the barrier)
// Epilogue: norms wave-reduced (shfl_xor 16,32) into LDS, then
// out = acc*(2/D) - nx[row] - nw[col]  (C/D layout per m89, unchanged).
// XCD slab remap: 16 consecutive wid (one bm-panel) -> same XCD L2.
// ---------------------------------------------------------------------------
__global__ __launch_bounds__(256, 3) void gemm_fused(
        const float* __restrict__ x, const float* __restrict__ Wm,
        float* __restrict__ out) {
    __shared__ ushort As[2 * 4096];   // 16 KB: 2 bufs x 8 A-tiles x 512
    __shared__ ushort Bs[2 * 4096];   // 16 KB
    __shared__ float  nx[128];        // row norms (block-local)
    __shared__ float  nw[128];        // col norms (block-local)

    const int tid  = threadIdx.x;
    const int lane = tid & 63;
    const int wv   = tid >> 6;          // [0,4)

    // 2048 blocks; 16 consecutive wid share bm (A panel) -> same XCD L2
    const int wid = (blockIdx.x & 7) * 256 + (blockIdx.x >> 3);
    const int bm  = wid >> 4;           // [0,128)
    const int bn  = wid & 15;           // [0,16)

    const int r16 = lane & 15;          // row within tile
    const int q   = lane >> 4;          // k-quarter

    // fp32 sources for the 4 tiles this wave converts: A{wv,wv+4}, B{wv,wv+4}
    const float* pa0 = x  + ((size_t)(bm * 128 + wv * 16       + r16)) * D_DIM + q * 8;
    const float* pa1 = x  + ((size_t)(bm * 128 + (wv + 4) * 16 + r16)) * D_DIM + q * 8;
    const float* pb0 = Wm + ((size_t)(bn * 128 + wv * 16       + r16)) * D_DIM + q * 8;
    const float* pb1 = Wm + ((size_t)(bn * 128 + (wv + 4) * 16 + r16)) * D_DIM + q * 8;

    // LDS chunk-write targets (lane*16B -> conflict-free b128 writes)
    ushort* wA0 = As + wv * 512       + lane * 8;
    ushort* wA1 = As + (wv + 4) * 512 + lane * 8;
    ushort* wB0 = Bs + wv * 512       + lane * 8;
    ushort* wB1 = Bs + (wv + 4) * 512 + lane * 8;

    // fragment-read bases (add buffer offset + tile*512 imm at use)
    const ushort* aRd = As + (wv >> 1) * 2048 + lane * 8;   // tiles (wv>>1)*4+mi
    const ushort* bRd = Bs + (wv & 1) * 2048 + lane * 8;    // tiles (wv&1)*4+ni

    float na0 = 0.f, na1 = 0.f, nb0 = 0.f, nb1 = 0.f;
    f32x4 A0l, A0h, A1l, A1h, B0l, B0h, B1l, B1h;   // static names (rule #20)

#define LOADK(kt) do { const int o_ = (kt) * 32;                  \
    A0l = *(const f32x4*)(pa0 + o_); A0h = *(const f32x4*)(pa0 + o_ + 4); \
    A1l = *(const f32x4*)(pa1 + o_); A1h = *(const f32x4*)(pa1 + o_ + 4); \
    B0l = *(const f32x4*)(pb0 + o_); B0h = *(const f32x4*)(pb0 + o_ + 4); \
    B1l = *(const f32x4*)(pb1 + o_); B1h = *(const f32x4*)(pb1 + o_ + 4); \
  } while (0)

#define NORMACC() do {                                            \
    na0 += sq4(A0l) + sq4(A0h); na1 += sq4(A1l) + sq4(A1h);       \
    nb0 += sq4(B0l) + sq4(B0h); nb1 += sq4(B1l) + sq4(B1h);       \
  } while (0)

#define CVTSTORE(bufO) do {                                       \
    pk8(wA0 + (bufO), A0l, A0h); pk8(wA1 + (bufO), A1l, A1h);     \
    pk8(wB0 + (bufO), B0l, B0h); pk8(wB1 + (bufO), B1l, B1h);     \
  } while (0)

    f32x4 acc[4][4];
    #pragma unroll
    for (int mi = 0; mi < 4; ++mi)
        #pragma unroll
        for (int ni = 0; ni < 4; ++ni)
            acc[mi][ni] = (f32x4){0.f, 0.f, 0.f, 0.f};

    // ---- prologue: convert kt=0 into buf0 ----
    LOADK(0);
    NORMACC();
    CVTSTORE(0);
    __syncthreads();

    #pragma unroll 2
    for (int kt = 0; kt < KT32; ++kt) {
        const int cur = (kt & 1) * 4096;
        const int nxt = cur ^ 4096;

        bf16x8 a[4], b[4];
        #pragma unroll
        for (int mi = 0; mi < 4; ++mi)
            a[mi] = *(const bf16x8*)(aRd + cur + mi * 512);
        #pragma unroll
        for (int ni = 0; ni < 4; ++ni)
            b[ni] = *(const bf16x8*)(bRd + cur + ni * 512);

        LOADK((kt + 1) & 31);   // next step's fp32 (L2-hot); wrap harmless

        PRIO1;
        #pragma unroll
        for (int mi = 0; mi < 4; ++mi)
            #pragma unroll
            for (int ni = 0; ni < 4; ++ni)
                acc[mi][ni] = __builtin_amdgcn_mfma_f32_16x16x32_bf16(
                    a[mi], b[ni], acc[mi][ni], 0, 0, 0);
        PRIO0;

        if (kt != 31) NORMACC();   // skip the wrapped kt=0 re-count
        CVTSTORE(nxt);             // wrapped store at kt=31 is never read
        __syncthreads();           // writes visible; buffer swap safe
    }

    // ---- norms: reduce lanes {r,r+16,r+32,r+48} -> full row sums ----
    const float inv = 1.0f / (float)D_DIM;
    float s0 = na0 * inv; s0 += __shfl_xor(s0, 16, 64); s0 += __shfl_xor(s0, 32, 64);
    float s1 = na1 * inv; s1 += __shfl_xor(s1, 16, 64); s1 += __shfl_xor(s1, 32, 64);
    float s2 = nb0 * inv; s2 += __shfl_xor(s2, 16, 64); s2 += __shfl_xor(s2, 32, 64);
    float s3 = nb1 * inv; s3 += __shfl_xor(s3, 16, 64); s3 += __shfl_xor(s3, 32, 64);
    if (lane < 16) {
        nx[wv * 16 + lane]       = s0;
        nx[(wv + 4) * 16 + lane] = s1;
        nw[wv * 16 + lane]       = s2;
        nw[(wv + 4) * 16 + lane] = s3;
    }
    __syncthreads();

    // ---- epilogue: C/D layout col=lane&15, row=(lane>>4)*4+reg (m89) ----
    const float scale = 2.0f / (float)D_DIM;
    const int rsel = lane & 15;
    const int quad = lane >> 4;
    const int lr0  = (wv >> 1) * 64 + quad * 4;   // local row base
    const int lc0  = (wv & 1) * 64 + rsel;        // local col base
    const int row0 = bm * 128 + lr0;
    const int col0 = bn * 128 + lc0;

    float x2r[4][4];
    #pragma unroll
    for (int mi = 0; mi < 4; ++mi)
        #pragma unroll
        for (int r = 0; r < 4; ++r)
            x2r[mi][r] = nx[lr0 + mi * 16 + r];

    #pragma unroll
    for (int ni = 0; ni < 4; ++ni) {
        const int c  = col0 + ni * 16;
        const float wc = nw[lc0 + ni * 16];
        #pragma unroll
        for (int mi = 0; mi < 4; ++mi) {
            #pragma unroll
            for (int r = 0; r < 4; ++r) {
                const int rr = row0 + mi * 16 + r;
                out[(size_t)rr * C_DIM + c] = acc[mi][ni][r] * scale - x2r[mi][r] - wc;
            }
        }
    }
#undef LOADK
#undef NORMACC
#undef CVTSTORE
}

// ---------------------------------------------------------------------------
extern "C" void kernel_launch(void* const* d_in, const int* in_sizes, int n_in,
                              void* d_out, int out_size, void* d_ws, size_t ws_size,
                              hipStream_t stream) {
    const float* x = (const float*)d_in[0];   // [B, D] fp32
    const float* W = (const float*)d_in[1];   // [C, D] fp32
    float* out = (float*)d_out;               // [B, C] fp32
    (void)d_ws; (void)ws_size;                // no workspace, no memset

    gemm_fused<<<(B_ROWS / 128) * (C_DIM / 128), 256, 0, stream>>>(x, W, out);
}

// Round 7
// 306.609 us; speedup vs baseline: 1.2938x; 1.2938x over previous
//
#include <hip/hip_runtime.h>
#include <hip/hip_bf16.h>
#include <stdint.h>

// EuclideanDeconf: x[B,D] fp32, W[C,D] fp32 -> out[B,C] fp32
// out = (2/D)*x.W^T - ||x||^2/D - ||w||^2/D
//
// R10: NO fragment repack in global memory. Key fact (from R6's analysis):
// a lane's mfma_f32_16x16x32_bf16 fragment (8 bf16) is 16 CONTIGUOUS bytes
// of a row-major bf16 matrix, and global_load_lds takes PER-LANE source
// addresses — so the gemm stages fragment-ordered LDS chunks directly from
// row-major bf16 by addressing lane l at row (l&15), k kt*32+(l>>4)*8.
// The pack pass is therefore a trivial coalesced fp32->bf16 row copy with
// shfl-reduced row norms (no atomics, no memset, no transpose) ~= 20 µs,
// replacing the 85-104 µs layout-shuffling pack of R0-R5.
#define B_ROWS 16384
#define D_DIM  1024
#define C_DIM  2048
#define KT32   (D_DIM / 32)    // 32 K-steps of 32

typedef short bf16x8 __attribute__((ext_vector_type(8)));   // 8 bf16 = 4 VGPRs
typedef float f32x4  __attribute__((ext_vector_type(4)));
typedef unsigned short us4 __attribute__((ext_vector_type(4)));  // 8 B

#define AS1 __attribute__((address_space(1)))
#define AS3 __attribute__((address_space(3)))
#define BARRIER __builtin_amdgcn_s_barrier()
#define LGKM0 asm volatile("s_waitcnt lgkmcnt(0)")
#define VMCNT(n) asm volatile("s_waitcnt vmcnt(" #n ")" ::: "memory")
#define PRIO1 __builtin_amdgcn_s_setprio(1)
#define PRIO0 __builtin_amdgcn_s_setprio(0)

__device__ __forceinline__ float sq4(f32x4 v) {
    return v[0]*v[0] + v[1]*v[1] + v[2]*v[2] + v[3]*v[3];
}

// ---------------------------------------------------------------------------
// pack_rows (R10): one wave per row. 4 passes of lane-consecutive f32x4
// reads (1 KB/instr, perfectly coalesced) -> cvt -> lane-consecutive 8 B
// bf16 stores (512 B/instr, dense). Row norm: full 6-step shfl_xor reduce,
// lane 0 writes norm[row] directly — ZERO atomics, no memset needed.
// 108 MB total traffic at HBM rate ~= 20 µs.
// ---------------------------------------------------------------------------
__global__ __launch_bounds__(256) void pack_rows(
        const float* __restrict__ x, const float* __restrict__ W,
        ushort* __restrict__ Abf, ushort* __restrict__ Bbf,
        float* __restrict__ x2, float* __restrict__ w2) {
    int row = blockIdx.x * 4 + (threadIdx.x >> 6);
    const int lane = threadIdx.x & 63;
    const float* src; ushort* dst; float* norm;
    if (row < B_ROWS) { src = x; dst = Abf; norm = x2; }
    else { row -= B_ROWS; src = W; dst = Bbf; norm = w2; }

    const float* rp = src + (size_t)row * D_DIM;
    ushort*      wp = dst + (size_t)row * D_DIM;

    float s = 0.f;
    #pragma unroll
    for (int p = 0; p < 4; ++p) {
        const int o = (p * 64 + lane) * 4;
        const f32x4 v = *(const f32x4*)(rp + o);
        s += sq4(v);
        ushort u[4]; __hip_bfloat16 h;
        h = __float2bfloat16(v[0]); u[0] = *(const ushort*)&h;
        h = __float2bfloat16(v[1]); u[1] = *(const ushort*)&h;
        h = __float2bfloat16(v[2]); u[2] = *(const ushort*)&h;
        h = __float2bfloat16(v[3]); u[3] = *(const ushort*)&h;
        *(us4*)(wp + o) = *(const us4*)u;
    }
    s += __shfl_xor(s, 1,  64);
    s += __shfl_xor(s, 2,  64);
    s += __shfl_xor(s, 4,  64);
    s += __shfl_xor(s, 8,  64);
    s += __shfl_xor(s, 16, 64);
    s += __shfl_xor(s, 32, 64);
    if (lane == 0) norm[row] = s * (1.0f / (float)D_DIM);
}

// ---------------------------------------------------------------------------
// gemm_tb (verified R2 structure; ONLY the staging source addresses changed):
// 128x128 tile, 4 waves 2x2, BK=32, TRIPLE-buffered LDS (48 KB -> 3
// blocks/CU, 12 waves/CU). Counted vmcnt(4) never drained to 0 (T4);
// setprio around the 16-MFMA cluster (T5); stage kt+2 into the buffer freed
// at kt-1. Staging now reads row-major bf16 with per-lane fragment-order
// addresses: lane l of chunk (tile,kt) <- Abf[tile*16+(l&15)][kt*32+(l>>4)*8]
// (16 B contiguous per lane; 16 rows x 64 B dense segments per instr).
// LDS dest stays linear lane*16 -> LDS content identical to R2's Apk chunks;
// ds_read/MFMA/epilogue bit-identical to R2.
// ---------------------------------------------------------------------------
__global__ __launch_bounds__(256, 3) void gemm_tb(
        const ushort* __restrict__ Abf, const ushort* __restrict__ Bbf,
        const float* __restrict__ x2, const float* __restrict__ w2,
        float* __restrict__ out) {
    __shared__ ushort As[3 * 4096];   // 24 KB: 3 bufs x 8 tiles x 512
    __shared__ ushort Bs[3 * 4096];   // 24 KB

    const int tid  = threadIdx.x;
    const int lane = tid & 63;
    const int wv   = tid >> 6;          // [0,4)

    const int wid = (blockIdx.x & 7) * 256 + (blockIdx.x >> 3);  // XCD slab
    const int bm  = wid >> 4;           // [0,128)
    const int bn  = wid & 15;           // [0,16)

    // per-lane fragment-order staging bases into ROW-MAJOR bf16 (ushorts):
    // row = panel + (lane&15), k-offset = (lane>>4)*8
    const ushort* aSrc = Abf + (size_t)(bm * 128 + (lane & 15)) * D_DIM + (lane >> 4) * 8;
    const ushort* bSrc = Bbf + (size_t)(bn * 128 + (lane & 15)) * D_DIM + (lane >> 4) * 8;
    // chunk (tile t, kstep ktc) instr offset: t*16*D_DIM + ktc*32 (ushorts)

    const ushort* aRd = As + (wv >> 1) * 2048 + lane * 8;   // tiles (wv>>1)*4+mi
    const ushort* bRd = Bs + (wv & 1) * 2048 + lane * 8;    // tiles (wv&1)*4+ni

    const int t0 = wv, t1 = wv + 4;

#define STAGE(ktc, bufO) do { \
    __builtin_amdgcn_global_load_lds( \
        (const AS1 void*)(aSrc + (size_t)t0 * 16 * D_DIM + (ktc) * 32), \
        (AS3 void*)(As + (bufO) + t0 * 512), 16, 0, 0); \
    __builtin_amdgcn_global_load_lds( \
        (const AS1 void*)(aSrc + (size_t)t1 * 16 * D_DIM + (ktc) * 32), \
        (AS3 void*)(As + (bufO) + t1 * 512), 16, 0, 0); \
    __builtin_amdgcn_global_load_lds( \
        (const AS1 void*)(bSrc + (size_t)t0 * 16 * D_DIM + (ktc) * 32), \
        (AS3 void*)(Bs + (bufO) + t0 * 512), 16, 0, 0); \
    __builtin_amdgcn_global_load_lds( \
        (const AS1 void*)(bSrc + (size_t)t1 * 16 * D_DIM + (ktc) * 32), \
        (AS3 void*)(Bs + (bufO) + t1 * 512), 16, 0, 0); \
  } while (0)

    f32x4 acc[4][4];
    #pragma unroll
    for (int mi = 0; mi < 4; ++mi)
        #pragma unroll
        for (int ni = 0; ni < 4; ++ni)
            acc[mi][ni] = (f32x4){0.f, 0.f, 0.f, 0.f};

    // ---- prologue: stage kt=0 -> buf0, kt=1 -> buf1 (8 loads in flight) ----
    STAGE(0, 0);
    STAGE(1, 4096);
    VMCNT(4);        // kt=0's 4 chunks landed; kt=1's 4 stay in flight
    BARRIER;

    int curO = 0, nxtO = 4096, stgO = 8192;   // rotating buffer offsets
    for (int kt = 0; kt < KT32; ++kt) {
        bf16x8 a[4], b[4];
        #pragma unroll
        for (int mi = 0; mi < 4; ++mi)
            a[mi] = *(const bf16x8*)(aRd + curO + mi * 512);
        #pragma unroll
        for (int ni = 0; ni < 4; ++ni)
            b[ni] = *(const bf16x8*)(bRd + curO + ni * 512);

        STAGE((kt + 2) & 31, stgO);   // into buffer freed at kt-1

        VMCNT(4);    // kt+1's 4 landed (issued one full phase ago); 4 in flight
        BARRIER;     // all waves' kt+1 chunks visible -> next phase safe
        LGKM0;
        PRIO1;
        #pragma unroll
        for (int mi = 0; mi < 4; ++mi)
            #pragma unroll
            for (int ni = 0; ni < 4; ++ni)
                acc[mi][ni] = __builtin_amdgcn_mfma_f32_16x16x32_bf16(
                    a[mi], b[ni], acc[mi][ni], 0, 0, 0);
        PRIO0;
        BARRIER;     // reads of buf(cur) done before anyone stages into it

        const int t = curO; curO = nxtO; nxtO = stgO; stgO = t;
    }

    // ---- epilogue: C/D layout col=lane&15, row=(lane>>4)*4+reg (m89) ----
    const float scale = 2.0f / (float)D_DIM;
    const int rsel = lane & 15;
    const int quad = lane >> 4;
    const int mT0  = bm * 8 + (wv >> 1) * 4;
    const int nT0  = bn * 8 + (wv & 1) * 4;
    const int row0 = mT0 * 16 + quad * 4;
    const int col0 = nT0 * 16 + rsel;

    float x2r[4][4];
    #pragma unroll
    for (int mi = 0; mi < 4; ++mi)
        #pragma unroll
        for (int r = 0; r < 4; ++r)
            x2r[mi][r] = x2[row0 + mi * 16 + r];

    #pragma unroll
    for (int ni = 0; ni < 4; ++ni) {
        const int c = col0 + ni * 16;
        const float wc = w2[c];
        #pragma unroll
        for (int mi = 0; mi < 4; ++mi) {
            #pragma unroll
            for (int r = 0; r < 4; ++r) {
                const int rr = row0 + mi * 16 + r;
                out[(size_t)rr * C_DIM + c] = acc[mi][ni][r] * scale - x2r[mi][r] - wc;
            }
        }
    }
#undef STAGE
}

// ---------------------------------------------------------------------------
extern "C" void kernel_launch(void* const* d_in, const int* in_sizes, int n_in,
                              void* d_out, int out_size, void* d_ws, size_t ws_size,
                              hipStream_t stream) {
    const float* x = (const float*)d_in[0];   // [B, D] fp32
    const float* W = (const float*)d_in[1];   // [C, D] fp32
    float* out = (float*)d_out;               // [B, C] fp32

    // ws: Abf (32 MB bf16 row-major) | Bbf (4 MB) | x2 (64 KB) | w2 (8 KB)
    char* ws = (char*)d_ws;
    ushort* Abf = (ushort*)ws;
    ushort* Bbf = (ushort*)(ws + (size_t)B_ROWS * D_DIM * sizeof(ushort));
    float*  x2  = (float*)(ws + (size_t)(B_ROWS + C_DIM) * D_DIM * sizeof(ushort));
    float*  w2  = x2 + B_ROWS;

    // no memset: pack_rows writes every x2/w2 entry exactly once (no atomics)
    pack_rows<<<(B_ROWS + C_DIM) / 4, 256, 0, stream>>>(
        x, W, Abf, Bbf, x2, w2);

    gemm_tb<<<(B_ROWS / 128) * (C_DIM / 128), 256, 0, stream>>>(
        Abf, Bbf, x2, w2, out);
}

// Round 8
// 289.865 us; speedup vs baseline: 1.3685x; 1.0578x over previous
//
#include <hip/hip_runtime.h>
#include <hip/hip_bf16.h>
#include <stdint.h>

// EuclideanDeconf: x[B,D] fp32, W[C,D] fp32 -> out[B,C] fp32
// out = (2/D)*x.W^T - ||x||^2/D - ||w||^2/D
//
// R11: A (the 32 MB side) is NEVER packed. The gemm stages fp32 x directly:
// a BK=32 chunk of fp32 is 16 rows x 128 B = FULL cache lines (the bf16
// row-major chunk was 16 x 64 B half-lines -> 2x transactions, R7's 146 µs).
// fp32->bf16 conversion happens in-register between ds_read and MFMA, and
// row norms x2 are accumulated in-gemm from the same fp32 fragments (no
// atomics, no extra pass). Only W (8 MB) is pre-packed (R0-verified path).
#define B_ROWS 16384
#define D_DIM  1024
#define C_DIM  2048
#define KT32   (D_DIM / 32)    // 32 K-steps of 32
#define NT_TOT (C_DIM  / 16)   // 128 n-tiles

typedef short bf16x8 __attribute__((ext_vector_type(8)));   // 8 bf16 = 4 VGPRs
typedef float f32x4  __attribute__((ext_vector_type(4)));

#define AS1 __attribute__((address_space(1)))
#define AS3 __attribute__((address_space(3)))
#define BARRIER __builtin_amdgcn_s_barrier()
#define LGKM0 asm volatile("s_waitcnt lgkmcnt(0)")
#define VMCNT(n) asm volatile("s_waitcnt vmcnt(" #n ")" ::: "memory")
#define PRIO1 __builtin_amdgcn_s_setprio(1)
#define PRIO0 __builtin_amdgcn_s_setprio(0)

__device__ __forceinline__ float sq4(f32x4 v) {
    return v[0]*v[0] + v[1]*v[1] + v[2]*v[2] + v[3]*v[3];
}

__device__ __forceinline__ bf16x8 pk8v(f32x4 lo, f32x4 hi) {
    ushort u[8]; __hip_bfloat16 h;
    h = __float2bfloat16(lo[0]); u[0] = *(const ushort*)&h;
    h = __float2bfloat16(lo[1]); u[1] = *(const ushort*)&h;
    h = __float2bfloat16(lo[2]); u[2] = *(const ushort*)&h;
    h = __float2bfloat16(lo[3]); u[3] = *(const ushort*)&h;
    h = __float2bfloat16(hi[0]); u[4] = *(const ushort*)&h;
    h = __float2bfloat16(hi[1]); u[5] = *(const ushort*)&h;
    h = __float2bfloat16(hi[2]); u[6] = *(const ushort*)&h;
    h = __float2bfloat16(hi[3]); u[7] = *(const ushort*)&h;
    return *(const bf16x8*)u;
}

// ---------------------------------------------------------------------------
// pack_w (R0-verified pack, W-only: 4096 chunks): fp32 W -> bf16 chunks in
// MFMA fragment order + w2 norms via atomicAdd. Only 12 MB of traffic ~ 4 µs.
// ---------------------------------------------------------------------------
__global__ __launch_bounds__(256) void pack_w(
        const float* __restrict__ W, ushort* __restrict__ Bpk,
        float* __restrict__ w2) {
    const int chunk = blockIdx.x * 4 + (threadIdx.x >> 6);
    const int lane  = threadIdx.x & 63;
    const int tile  = chunk >> 5;
    const int kt    = chunk & 31;
    const int row   = tile * 16 + (lane & 15);
    const int k0    = kt * 32 + (lane >> 4) * 8;
    const f32x4 v0 = *(const f32x4*)(W + (size_t)row * D_DIM + k0);
    const f32x4 v1 = *(const f32x4*)(W + (size_t)row * D_DIM + k0 + 4);
    float s = sq4(v0) + sq4(v1);
    *(bf16x8*)(Bpk + ((size_t)chunk * 64 + lane) * 8) = pk8v(v0, v1);
    s += __shfl_xor(s, 16, 64);
    s += __shfl_xor(s, 32, 64);
    if (lane < 16) atomicAdd(w2 + tile * 16 + lane, s * (1.0f / (float)D_DIM));
}

// ---------------------------------------------------------------------------
// gemm_af32: 128x128 tile, 4 waves 2x2 (wave tile 64x64), BK=32, triple-ring
// (R2-verified discipline: stage kt+2 into slot freed at kt-1, counted
// VMCNT(6) never drained to 0, setprio around MFMA, 2 barriers/step).
//
// A staging (fp32, full lines): instr = 8 rows x 128 B. Lane l sources
//   row = tile*16 + half*8 + (l>>3), col16 = (l&7) ^ (l>>3)   [16B units]
// -> per instr 8 full 128B lines, per-lane XOR-permuted within the row.
// Linear LDS dest => LDS tile layout addr = r*128 + (c16 ^ (r&7))*16.
// Fragment read (row r=l&15, floats q*8..q*8+7, q=l>>4): two b128 at
//   c16 = (2q)^(r&7) and that ^1  => addr aLo = r*32+((2q)^(r&7))*4 (floats),
//   aHi = aLo^4. Bank check: for fixed q, c16 spans all 8 values over r
//   => 8 lanes per bank-quad = 2/bank = FREE (m136).
// B staging: contiguous 1 KB packed chunks (R2 path, unchanged).
// Per step/wave: 8 A-b128 + 4 B-b128 ds_reads, 4+2 gload_lds, 32 cvt +
// 32 sq-FMA VALU (coexists with MFMA pipe, m114), 16 MFMA.
// x2: nxa[mi] += sq(fp32 frags); end: shfl_xor(16,32) -> nx LDS -> epilogue.
// LDS: As 48 KB + Bs 24 KB + nx 0.5 KB = 72.5 KB -> 2 blocks/CU.
// ---------------------------------------------------------------------------
__global__ __launch_bounds__(256, 2) void gemm_af32(
        const float* __restrict__ x, const ushort* __restrict__ Bpk,
        const float* __restrict__ w2, float* __restrict__ out) {
    __shared__ float  As[3 * 4096];   // 48 KB: 3 slots x 8 tiles x 512 floats
    __shared__ ushort Bs[3 * 4096];   // 24 KB: 3 slots x 8 tiles x 512 ushorts
    __shared__ float  nx[128];        // block-local row norms

    const int tid  = threadIdx.x;
    const int lane = tid & 63;
    const int wv   = tid >> 6;          // [0,4)

    // 2048 blocks; 16 consecutive wid share bm (A panel) -> same XCD L2
    const int wid = (blockIdx.x & 7) * 256 + (blockIdx.x >> 3);
    const int bm  = wid >> 4;           // [0,128)
    const int bn  = wid & 15;           // [0,16)

    // A staging per-lane base (floats): row (lane>>3), col16 (lane&7)^(lane>>3)
    const float* aStage = x + (size_t)(bm * 128 + (lane >> 3)) * D_DIM
                            + ((lane & 7) ^ (lane >> 3)) * 4;
    // B staging base (packed chunks)
    const ushort* bStage = Bpk + ((size_t)(bn * 8) * KT32) * 512 + lane * 8;

    // A fragment-read offsets (float units, within 512-float tile slab)
    const int r = lane & 15;
    const int q = lane >> 4;
    const int aLo = r * 32 + (((2 * q) ^ (r & 7)) * 4);
    const int aHi = aLo ^ 4;
    const float*  aRdL = As + (wv >> 1) * 2048 + aLo;   // + slot*4096 + mi*512
    const float*  aRdH = As + (wv >> 1) * 2048 + aHi;
    const ushort* bRd  = Bs + (wv & 1) * 2048 + lane * 8;

#define GLL(src, dst) __builtin_amdgcn_global_load_lds( \
        (const AS1 void*)(src), (AS3 void*)(dst), 16, 0, 0)
    // wave stages A tiles {wv, wv+4} (2 instr each) + B tiles {wv, wv+4}
#define STAGE(ktc, s) do { \
    GLL(aStage + (size_t)(wv * 16 + 0)       * D_DIM + (ktc) * 32, As + (s) * 4096 + wv * 512); \
    GLL(aStage + (size_t)(wv * 16 + 8)       * D_DIM + (ktc) * 32, As + (s) * 4096 + wv * 512 + 256); \
    GLL(aStage + (size_t)((wv + 4) * 16 + 0) * D_DIM + (ktc) * 32, As + (s) * 4096 + (wv + 4) * 512); \
    GLL(aStage + (size_t)((wv + 4) * 16 + 8) * D_DIM + (ktc) * 32, As + (s) * 4096 + (wv + 4) * 512 + 256); \
    GLL(bStage + ((size_t)wv       * KT32 + (ktc)) * 512, Bs + (s) * 4096 + wv * 512); \
    GLL(bStage + ((size_t)(wv + 4) * KT32 + (ktc)) * 512, Bs + (s) * 4096 + (wv + 4) * 512); \
  } while (0)

    f32x4 acc[4][4];
    #pragma unroll
    for (int mi = 0; mi < 4; ++mi)
        #pragma unroll
        for (int ni = 0; ni < 4; ++ni)
            acc[mi][ni] = (f32x4){0.f, 0.f, 0.f, 0.f};
    float nxa[4] = {0.f, 0.f, 0.f, 0.f};

    // ---- prologue: stage kt=0 -> slot0, kt=1 -> slot1 (12 loads in flight) ----
    STAGE(0, 0);
    STAGE(1, 1);
    VMCNT(6);        // kt=0's 6 landed; kt=1's 6 stay in flight
    BARRIER;

    int cur = 0, nxt = 1, stg = 2;
    for (int kt = 0; kt < KT32; ++kt) {
        // frag reads from slot cur (data waited one step ago)
        f32x4 al[4], ah[4]; bf16x8 b[4];
        #pragma unroll
        for (int mi = 0; mi < 4; ++mi) {
            al[mi] = *(const f32x4*)(aRdL + cur * 4096 + mi * 512);
            ah[mi] = *(const f32x4*)(aRdH + cur * 4096 + mi * 512);
        }
        #pragma unroll
        for (int ni = 0; ni < 4; ++ni)
            b[ni] = *(const bf16x8*)(bRd + cur * 4096 + ni * 512);

        STAGE((kt + 2) & 31, stg);   // into slot freed at kt-1 (wrap harmless)

        VMCNT(6);    // kt+1's 6 landed (issued one full step ago); 6 in flight
        BARRIER;     // all waves' kt+1 writes visible
        LGKM0;

        // cvt + norm accumulate (VALU pipe; coexists with MFMA per m114)
        bf16x8 a[4];
        #pragma unroll
        for (int mi = 0; mi < 4; ++mi) {
            nxa[mi] += sq4(al[mi]) + sq4(ah[mi]);
            a[mi] = pk8v(al[mi], ah[mi]);
        }

        PRIO1;
        #pragma unroll
        for (int mi = 0; mi < 4; ++mi)
            #pragma unroll
            for (int ni = 0; ni < 4; ++ni)
                acc[mi][ni] = __builtin_amdgcn_mfma_f32_16x16x32_bf16(
                    a[mi], b[ni], acc[mi][ni], 0, 0, 0);
        PRIO0;
        BARRIER;     // reads of cur done before anyone stages into it

        const int t = cur; cur = nxt; nxt = stg; stg = t;
    }

    // ---- x2: lanes {r,r+16,r+32,r+48} hold the 4 quarter-sums of row r ----
    const float inv = 1.0f / (float)D_DIM;
    #pragma unroll
    for (int mi = 0; mi < 4; ++mi) {
        float s = nxa[mi] * inv;
        s += __shfl_xor(s, 16, 64);
        s += __shfl_xor(s, 32, 64);
        if (!(wv & 1) && lane < 16)           // waves 0,2 (wave 1,3 duplicate)
            nx[(wv >> 1) * 64 + mi * 16 + lane] = s;
    }
    __syncthreads();

    // ---- epilogue: C/D layout col=lane&15, row=(lane>>4)*4+reg (m89) ----
    const float scale = 2.0f / (float)D_DIM;
    const int rsel = lane & 15;
    const int quad = lane >> 4;
    const int lr0  = (wv >> 1) * 64 + quad * 4;   // local row base
    const int row0 = bm * 128 + lr0;
    const int col0 = bn * 128 + (wv & 1) * 64 + rsel;

    float x2r[4][4];
    #pragma unroll
    for (int mi = 0; mi < 4; ++mi)
        #pragma unroll
        for (int rr = 0; rr < 4; ++rr)
            x2r[mi][rr] = nx[lr0 + mi * 16 + rr];

    #pragma unroll
    for (int ni = 0; ni < 4; ++ni) {
        const int c = col0 + ni * 16;
        const float wc = w2[c];
        #pragma unroll
        for (int mi = 0; mi < 4; ++mi) {
            #pragma unroll
            for (int rr = 0; rr < 4; ++rr) {
                const int gr = row0 + mi * 16 + rr;
                out[(size_t)gr * C_DIM + c] = acc[mi][ni][rr] * scale - x2r[mi][rr] - wc;
            }
        }
    }
#undef STAGE
#undef GLL
}

// ---------------------------------------------------------------------------
extern "C" void kernel_launch(void* const* d_in, const int* in_sizes, int n_in,
                              void* d_out, int out_size, void* d_ws, size_t ws_size,
                              hipStream_t stream) {
    const float* x = (const float*)d_in[0];   // [B, D] fp32
    const float* W = (const float*)d_in[1];   // [C, D] fp32
    float* out = (float*)d_out;               // [B, C] fp32

    // ws: Bpk (4 MB bf16 packed W chunks) | w2 (8 KB)
    char* ws = (char*)d_ws;
    ushort* Bpk = (ushort*)ws;
    float*  w2  = (float*)(ws + (size_t)C_DIM * D_DIM * sizeof(ushort));

    hipMemsetAsync(w2, 0, C_DIM * sizeof(float), stream);

    pack_w<<<NT_TOT * KT32 / 4, 256, 0, stream>>>(W, Bpk, w2);

    gemm_af32<<<(B_ROWS / 128) * (C_DIM / 128), 256, 0, stream>>>(
        x, Bpk, w2, out);
}

// Round 9
// 249.131 us; speedup vs baseline: 1.5923x; 1.1635x over previous
//
#include <hip/hip_runtime.h>
#include <hip/hip_bf16.h>
#include <stdint.h>

// EuclideanDeconf: x[B,D] fp32, W[C,D] fp32 -> out[B,C] fp32
// out = (2/D)*x.W^T - ||x||^2/D - ||w||^2/D
// R12: R2-exact gemm (best verified, 77 µs) + pack restructured tile-per-block:
// no atomics, no memset dispatch, 1152 blocks (was 9216+memset). Same per-lane
// read/write pattern as the R0-verified pack -> same memory behavior, less
// overhead. gemm staging/content bit-identical to R2.
#define B_ROWS 16384
#define D_DIM  1024
#define C_DIM  2048
#define KT32   (D_DIM / 32)    // 32 K-steps of 32 (= pack chunk granularity)
#define MT_TOT (B_ROWS / 16)   // 1024 m-tiles
#define NT_TOT (C_DIM  / 16)   // 128  n-tiles

typedef short bf16x8 __attribute__((ext_vector_type(8)));   // 8 bf16 = 4 VGPRs
typedef float f32x4  __attribute__((ext_vector_type(4)));

#define AS1 __attribute__((address_space(1)))
#define AS3 __attribute__((address_space(3)))
#define BARRIER __builtin_amdgcn_s_barrier()
#define LGKM0 asm volatile("s_waitcnt lgkmcnt(0)")
#define VMCNT(n) asm volatile("s_waitcnt vmcnt(" #n ")" ::: "memory")
#define PRIO1 __builtin_amdgcn_s_setprio(1)
#define PRIO0 __builtin_amdgcn_s_setprio(0)

__device__ __forceinline__ float sq4(f32x4 v) {
    return v[0]*v[0] + v[1]*v[1] + v[2]*v[2] + v[3]*v[3];
}

__device__ __forceinline__ bf16x8 pk8v(f32x4 lo, f32x4 hi) {
    ushort u[8]; __hip_bfloat16 h;
    h = __float2bfloat16(lo[0]); u[0] = *(const ushort*)&h;
    h = __float2bfloat16(lo[1]); u[1] = *(const ushort*)&h;
    h = __float2bfloat16(lo[2]); u[2] = *(const ushort*)&h;
    h = __float2bfloat16(lo[3]); u[3] = *(const ushort*)&h;
    h = __float2bfloat16(hi[0]); u[4] = *(const ushort*)&h;
    h = __float2bfloat16(hi[1]); u[5] = *(const ushort*)&h;
    h = __float2bfloat16(hi[2]); u[6] = *(const ushort*)&h;
    h = __float2bfloat16(hi[3]); u[7] = *(const ushort*)&h;
    return *(const bf16x8*)u;
}

// ---------------------------------------------------------------------------
// pack_tile (R12): one block per 16-row tile; wave wv handles K-chunks
// kt = wv*8 .. wv*8+7. Per iter, lane l reads 2 float4s at
// (row = tile*16 + (l&15), k = kt*32 + (l>>4)*8) — 16 full 128 B lines per
// instr pair, each line fully consumed (verified pattern from the R0 pack) —
// and writes the chunk as a contiguous 1 KB bf16x8 store (identical chunk
// format to R0/R2). Row-norm partials accumulate in-register across the
// wave's 8 chunks; shfl_xor(16,32) folds the 4 k-quarters; the 4 wave
// partials combine through LDS; wave 0 stores x2/w2 directly.
// ZERO atomics, ZERO memset, 1152 blocks.
// ---------------------------------------------------------------------------
__global__ __launch_bounds__(256) void pack_tile(
        const float* __restrict__ x, const float* __restrict__ W,
        ushort* __restrict__ Apk, ushort* __restrict__ Bpk,
        float* __restrict__ x2, float* __restrict__ w2) {
    __shared__ float part[4][16];

    int tile = blockIdx.x;
    const float* src; ushort* dst; float* norm;
    if (tile < MT_TOT) { src = x; dst = Apk; norm = x2; }
    else               { tile -= MT_TOT; src = W; dst = Bpk; norm = w2; }

    const int wv   = threadIdx.x >> 6;      // [0,4): k-quarter of the tile
    const int lane = threadIdx.x & 63;
    const int row  = tile * 16 + (lane & 15);
    const int q    = lane >> 4;

    const float* rp = src + (size_t)row * D_DIM + q * 8;
    ushort*      wp = dst + ((size_t)tile * KT32) * 512 + lane * 8;

    float s = 0.f;
    #pragma unroll 4
    for (int i = 0; i < 8; ++i) {
        const int kt = wv * 8 + i;
        const f32x4 v0 = *(const f32x4*)(rp + kt * 32);
        const f32x4 v1 = *(const f32x4*)(rp + kt * 32 + 4);
        s += sq4(v0) + sq4(v1);
        *(bf16x8*)(wp + (size_t)kt * 512) = pk8v(v0, v1);
    }
    // fold the 4 k-quarters: lanes {r, r+16, r+32, r+48} -> row partial
    s += __shfl_xor(s, 16, 64);
    s += __shfl_xor(s, 32, 64);
    if (lane < 16) part[wv][lane] = s;
    __syncthreads();
    if (wv == 0 && lane < 16)
        norm[tile * 16 + lane] =
            (part[0][lane] + part[1][lane] + part[2][lane] + part[3][lane])
            * (1.0f / (float)D_DIM);
}

// ---------------------------------------------------------------------------
// gemm_tb (verified R2, restored verbatim): 128x128 tile, 4 waves 2x2,
// BK=32, TRIPLE-buffered LDS (3 x 16 KB = 48 KB -> 3 blocks/CU, 12 waves/CU).
// Counted vmcnt(4) never drained to 0 (T4); setprio around the 16-MFMA
// cluster (T5); stage kt+2 into the buffer freed at kt-1. Cross-block TLP
// (3 blocks/CU) hides barrier stalls and the epilogue.
// ---------------------------------------------------------------------------
__global__ __launch_bounds__(256, 3) void gemm_tb(
        const ushort* __restrict__ Apk, const ushort* __restrict__ Bpk,
        const float* __restrict__ x2, const float* __restrict__ w2,
        float* __restrict__ out) {
    __shared__ ushort As[3 * 4096];   // 24 KB: 3 bufs x 8 tiles x 512
    __shared__ ushort Bs[3 * 4096];   // 24 KB

    const int tid  = threadIdx.x;
    const int lane = tid & 63;
    const int wv   = tid >> 6;          // [0,4)

    const int wid = (blockIdx.x & 7) * 256 + (blockIdx.x >> 3);  // XCD slab
    const int bm  = wid >> 4;           // [0,128)
    const int bn  = wid & 15;           // [0,16)

    const ushort* aSrc = Apk + ((size_t)(bm * 8) * KT32) * 512 + lane * 8;
    const ushort* bSrc = Bpk + ((size_t)(bn * 8) * KT32) * 512 + lane * 8;

    const ushort* aRd = As + (wv >> 1) * 2048 + lane * 8;   // tiles (wv>>1)*4+mi
    const ushort* bRd = Bs + (wv & 1) * 2048 + lane * 8;    // tiles (wv&1)*4+ni

    const int t0 = wv, t1 = wv + 4;

#define STAGE(ktc, bufO) do { \
    __builtin_amdgcn_global_load_lds( \
        (const AS1 void*)(aSrc + ((size_t)t0 * KT32 + (ktc)) * 512), \
        (AS3 void*)(As + (bufO) + t0 * 512), 16, 0, 0); \
    __builtin_amdgcn_global_load_lds( \
        (const AS1 void*)(aSrc + ((size_t)t1 * KT32 + (ktc)) * 512), \
        (AS3 void*)(As + (bufO) + t1 * 512), 16, 0, 0); \
    __builtin_amdgcn_global_load_lds( \
        (const AS1 void*)(bSrc + ((size_t)t0 * KT32 + (ktc)) * 512), \
        (AS3 void*)(Bs + (bufO) + t0 * 512), 16, 0, 0); \
    __builtin_amdgcn_global_load_lds( \
        (const AS1 void*)(bSrc + ((size_t)t1 * KT32 + (ktc)) * 512), \
        (AS3 void*)(Bs + (bufO) + t1 * 512), 16, 0, 0); \
  } while (0)

    f32x4 acc[4][4];
    #pragma unroll
    for (int mi = 0; mi < 4; ++mi)
        #pragma unroll
        for (int ni = 0; ni < 4; ++ni)
            acc[mi][ni] = (f32x4){0.f, 0.f, 0.f, 0.f};

    // ---- prologue: stage kt=0 -> buf0, kt=1 -> buf1 (8 loads in flight) ----
    STAGE(0, 0);
    STAGE(1, 4096);
    VMCNT(4);        // kt=0's 4 chunks landed; kt=1's 4 stay in flight
    BARRIER;

    int curO = 0, nxtO = 4096, stgO = 8192;   // rotating buffer offsets
    for (int kt = 0; kt < KT32; ++kt) {
        bf16x8 a[4], b[4];
        #pragma unroll
        for (int mi = 0; mi < 4; ++mi)
            a[mi] = *(const bf16x8*)(aRd + curO + mi * 512);
        #pragma unroll
        for (int ni = 0; ni < 4; ++ni)
            b[ni] = *(const bf16x8*)(bRd + curO + ni * 512);

        STAGE((kt + 2) & 31, stgO);   // into buffer freed at kt-1

        VMCNT(4);    // kt+1's 4 landed (issued one full phase ago); 4 in flight
        BARRIER;     // all waves' kt+1 chunks visible -> next phase safe
        LGKM0;
        PRIO1;
        #pragma unroll
        for (int mi = 0; mi < 4; ++mi)
            #pragma unroll
            for (int ni = 0; ni < 4; ++ni)
                acc[mi][ni] = __builtin_amdgcn_mfma_f32_16x16x32_bf16(
                    a[mi], b[ni], acc[mi][ni], 0, 0, 0);
        PRIO0;
        BARRIER;     // reads of buf(cur) done before anyone stages into it

        const int t = curO; curO = nxtO; nxtO = stgO; stgO = t;
    }

    // ---- epilogue: C/D layout col=lane&15, row=(lane>>4)*4+reg (m89) ----
    const float scale = 2.0f / (float)D_DIM;
    const int rsel = lane & 15;
    const int quad = lane >> 4;
    const int mT0  = bm * 8 + (wv >> 1) * 4;
    const int nT0  = bn * 8 + (wv & 1) * 4;
    const int row0 = mT0 * 16 + quad * 4;
    const int col0 = nT0 * 16 + rsel;

    float x2r[4][4];
    #pragma unroll
    for (int mi = 0; mi < 4; ++mi)
        #pragma unroll
        for (int r = 0; r < 4; ++r)
            x2r[mi][r] = x2[row0 + mi * 16 + r];

    #pragma unroll
    for (int ni = 0; ni < 4; ++ni) {
        const int c = col0 + ni * 16;
        const float wc = w2[c];
        #pragma unroll
        for (int mi = 0; mi < 4; ++mi) {
            #pragma unroll
            for (int r = 0; r < 4; ++r) {
                const int rr = row0 + mi * 16 + r;
                out[(size_t)rr * C_DIM + c] = acc[mi][ni][r] * scale - x2r[mi][r] - wc;
            }
        }
    }
#undef STAGE
}

// ---------------------------------------------------------------------------
extern "C" void kernel_launch(void* const* d_in, const int* in_sizes, int n_in,
                              void* d_out, int out_size, void* d_ws, size_t ws_size,
                              hipStream_t stream) {
    const float* x = (const float*)d_in[0];   // [B, D] fp32
    const float* W = (const float*)d_in[1];   // [C, D] fp32
    float* out = (float*)d_out;               // [B, C] fp32

    // ws: Apk (32 MB bf16 packed) | Bpk (4 MB) | x2 (64 KB) | w2 (8 KB)
    char* ws = (char*)d_ws;
    ushort* Apk = (ushort*)ws;
    ushort* Bpk = (ushort*)(ws + (size_t)B_ROWS * D_DIM * sizeof(ushort));
    float*  x2  = (float*)(ws + (size_t)(B_ROWS + C_DIM) * D_DIM * sizeof(ushort));
    float*  w2  = x2 + B_ROWS;

    // no memset: pack_tile writes every x2/w2 entry exactly once (no atomics)
    pack_tile<<<MT_TOT + NT_TOT, 256, 0, stream>>>(x, W, Apk, Bpk, x2, w2);

    gemm_tb<<<(B_ROWS / 128) * (C_DIM / 128), 256, 0, stream>>>(
        Apk, Bpk, x2, w2, out);
}